// Round 13
// baseline (115.694 us; speedup 1.0000x reference)
//
#include <hip/hip_runtime.h>
#include <hip/hip_fp16.h>
#include <float.h>

#define C_    512
#define H_    38
#define W_    50
#define HW_   (H_ * W_)       // 1900
#define NROIS 1024
#define PS    7
#define PRE   14              // PS*2
#define NCELL 49              // PS*PS
#define NGP   (PRE * PRE)     // 196 gridpoints
#define OTP   516             // outtile row stride (halfwords): 8B-aligned rows,
                              // flush bank stride 2 -> ~2-way only
#define CPB   25              // cells per block (2 blocks/ROI, overlap cell 24)

typedef float vfloat4 __attribute__((ext_vector_type(4)));
typedef _Float16 h2 __attribute__((ext_vector_type(2)));

__device__ inline h2 bch2u(unsigned v)   { return __builtin_bit_cast(h2, v); }
__device__ inline unsigned bcu(h2 v)     { return __builtin_bit_cast(unsigned, v); }

// ---------------------------------------------------------------------------
// Transpose + downconvert: bottom (C, H*W) f32 -> (H*W, C) fp16.
// ---------------------------------------------------------------------------
__global__ __launch_bounds__(256) void transpose_kernel(
    const float* __restrict__ in, _Float16* __restrict__ out) {
    __shared__ float tile[32][33];
    const int pix0 = blockIdx.x * 32;
    const int c0   = blockIdx.y * 32;
    const int tx = threadIdx.x & 31;
    const int ty = threadIdx.x >> 5;

    for (int i = ty; i < 32; i += 8) {
        int c = c0 + i, pix = pix0 + tx;
        tile[i][tx] = (pix < HW_) ? in[c * HW_ + pix] : 0.0f;
    }
    __syncthreads();
    for (int i = ty; i < 32; i += 8) {
        int pix = pix0 + i, c = c0 + tx;
        if (pix < HW_) out[pix * C_ + c] = (_Float16)tile[tx][i];
    }
}

// ---------------------------------------------------------------------------
// Main crop-and-maxpool kernel (transposed fp16 src: src[pix*512 + c]).
// grid = (NROIS, 2); block = 512 (8 waves). Block (n, half) handles ROI n,
// cells [half*24, half*24+25) — both halves 25 cells (cell 24 overlaps,
// identical values). Wave covers ALL 512 channels (lane owns 8 ch = 16B):
// corner load = ONE contiguous aligned 1KB single-segment wave-load.
// Cell body split into two 2-gridpoint chunks (8 outstanding uint4) to fit
// 64 VGPR -> launch_bounds(512,8) -> 4 blocks/CU = 32 waves (100%).
// LDS: outtile [cl][c] stride 516 (conflict-free b64 writes) + tables
// = 31.3 KB/block.
// ---------------------------------------------------------------------------
__global__ __launch_bounds__(512, 8) void croppool_kernel(
    const _Float16* __restrict__ src, const float* __restrict__ rois,
    float* __restrict__ out) {

    const int n    = blockIdx.x;
    const int half = blockIdx.y;
    const int cellLo = half * 24;
    const int tid  = threadIdx.x;

    __shared__ _Float16 outtile[CPB * OTP];     // 25800 B
    __shared__ int4  offt[NGP];                 // 3136 B
    __shared__ uint4 wgtt[NGP];                 // 3136 B

    // --- per-gridpoint tables (align_corners=True + zeros padding) ---
    if (tid < NGP) {
        const int gy = tid / PRE, gx = tid - PRE * gy;
        const float rx1 = rois[n * 5 + 1] * 0.0625f;
        const float ry1 = rois[n * 5 + 2] * 0.0625f;
        const float rx2 = rois[n * 5 + 3] * 0.0625f;
        const float ry2 = rois[n * 5 + 4] * 0.0625f;

        int xi0, xi1, yi0, yi1;
        float wx0, wx1, wy0, wy1;
        {   // x axis
            const float sz = (float)(W_ - 1);
            const float t0 = (rx2 - rx1) / sz, tc = (rx1 + rx2 - sz) / sz;
            const float base = -1.0f + (float)gx * (2.0f / 13.0f);
            const float coord = (t0 * base + tc + 1.0f) * 0.5f * sz;
            const float f = floorf(coord), a = coord - f;
            const int i0 = (int)f, i1 = i0 + 1;
            wx0 = (i0 >= 0 && i0 <= W_ - 1) ? (1.0f - a) : 0.0f;
            wx1 = (i1 >= 0 && i1 <= W_ - 1) ? a : 0.0f;
            xi0 = min(max(i0, 0), W_ - 1);
            xi1 = min(max(i1, 0), W_ - 1);
        }
        {   // y axis
            const float sz = (float)(H_ - 1);
            const float t0 = (ry2 - ry1) / sz, tc = (ry1 + ry2 - sz) / sz;
            const float base = -1.0f + (float)gy * (2.0f / 13.0f);
            const float coord = (t0 * base + tc + 1.0f) * 0.5f * sz;
            const float f = floorf(coord), a = coord - f;
            const int i0 = (int)f, i1 = i0 + 1;
            wy0 = (i0 >= 0 && i0 <= H_ - 1) ? (1.0f - a) : 0.0f;
            wy1 = (i1 >= 0 && i1 <= H_ - 1) ? a : 0.0f;
            yi0 = min(max(i0, 0), H_ - 1);
            yi1 = min(max(i1, 0), H_ - 1);
        }
        offt[tid] = make_int4((yi0 * W_ + xi0) * C_, (yi0 * W_ + xi1) * C_,
                              (yi1 * W_ + xi0) * C_, (yi1 * W_ + xi1) * C_);
        const _Float16 w0 = (_Float16)(wy0 * wx0);
        const _Float16 w1 = (_Float16)(wy0 * wx1);
        const _Float16 w2 = (_Float16)(wy1 * wx0);
        const _Float16 w3 = (_Float16)(wy1 * wx1);
        uint4 wv;
        wv.x = bcu((h2){w0, w0});
        wv.y = bcu((h2){w1, w1});
        wv.z = bcu((h2){w2, w2});
        wv.w = bcu((h2){w3, w3});
        wgtt[tid] = wv;
    }
    __syncthreads();

    const int lane = tid & 63;
    const int wave = tid >> 6;                 // 0..7
    const _Float16* srcc = src + 8 * lane;     // lane's 8 channels

    for (int cl = wave; cl < CPB; cl += 8) {
        const int cell = cellLo + cl;
        const int py = cell / PS, px = cell - PS * py;
        const int gb = 2 * py * PRE + 2 * px;

        h2 m0, m1, m2, m3;

        // ---- chunk A: gridpoints gb, gb+1 (8 outstanding 1KB loads) ----
        {
            const int4  oa = offt[gb],  ob = offt[gb + 1];
            const uint4 wa = wgtt[gb],  wb = wgtt[gb + 1];
            const uint4 A0 = *(const uint4*)(srcc + oa.x);
            const uint4 A1 = *(const uint4*)(srcc + oa.y);
            const uint4 A2 = *(const uint4*)(srcc + oa.z);
            const uint4 A3 = *(const uint4*)(srcc + oa.w);
            const uint4 B0 = *(const uint4*)(srcc + ob.x);
            const uint4 B1 = *(const uint4*)(srcc + ob.y);
            const uint4 B2 = *(const uint4*)(srcc + ob.z);
            const uint4 B3 = *(const uint4*)(srcc + ob.w);

            {
                const h2 w0 = bch2u(wa.x), w1 = bch2u(wa.y), w2 = bch2u(wa.z), w3 = bch2u(wa.w);
                m0 = w0 * bch2u(A0.x) + w1 * bch2u(A1.x) + w2 * bch2u(A2.x) + w3 * bch2u(A3.x);
                m1 = w0 * bch2u(A0.y) + w1 * bch2u(A1.y) + w2 * bch2u(A2.y) + w3 * bch2u(A3.y);
                m2 = w0 * bch2u(A0.z) + w1 * bch2u(A1.z) + w2 * bch2u(A2.z) + w3 * bch2u(A3.z);
                m3 = w0 * bch2u(A0.w) + w1 * bch2u(A1.w) + w2 * bch2u(A2.w) + w3 * bch2u(A3.w);
            }
            {
                const h2 w0 = bch2u(wb.x), w1 = bch2u(wb.y), w2 = bch2u(wb.z), w3 = bch2u(wb.w);
                m0 = __builtin_elementwise_max(m0, w0 * bch2u(B0.x) + w1 * bch2u(B1.x) + w2 * bch2u(B2.x) + w3 * bch2u(B3.x));
                m1 = __builtin_elementwise_max(m1, w0 * bch2u(B0.y) + w1 * bch2u(B1.y) + w2 * bch2u(B2.y) + w3 * bch2u(B3.y));
                m2 = __builtin_elementwise_max(m2, w0 * bch2u(B0.z) + w1 * bch2u(B1.z) + w2 * bch2u(B2.z) + w3 * bch2u(B3.z));
                m3 = __builtin_elementwise_max(m3, w0 * bch2u(B0.w) + w1 * bch2u(B1.w) + w2 * bch2u(B2.w) + w3 * bch2u(B3.w));
            }
        }

        // ---- chunk B: gridpoints gb+PRE, gb+PRE+1 ----
        {
            const int4  oa = offt[gb + PRE],  ob = offt[gb + PRE + 1];
            const uint4 wa = wgtt[gb + PRE],  wb = wgtt[gb + PRE + 1];
            const uint4 A0 = *(const uint4*)(srcc + oa.x);
            const uint4 A1 = *(const uint4*)(srcc + oa.y);
            const uint4 A2 = *(const uint4*)(srcc + oa.z);
            const uint4 A3 = *(const uint4*)(srcc + oa.w);
            const uint4 B0 = *(const uint4*)(srcc + ob.x);
            const uint4 B1 = *(const uint4*)(srcc + ob.y);
            const uint4 B2 = *(const uint4*)(srcc + ob.z);
            const uint4 B3 = *(const uint4*)(srcc + ob.w);

            {
                const h2 w0 = bch2u(wa.x), w1 = bch2u(wa.y), w2 = bch2u(wa.z), w3 = bch2u(wa.w);
                m0 = __builtin_elementwise_max(m0, w0 * bch2u(A0.x) + w1 * bch2u(A1.x) + w2 * bch2u(A2.x) + w3 * bch2u(A3.x));
                m1 = __builtin_elementwise_max(m1, w0 * bch2u(A0.y) + w1 * bch2u(A1.y) + w2 * bch2u(A2.y) + w3 * bch2u(A3.y));
                m2 = __builtin_elementwise_max(m2, w0 * bch2u(A0.z) + w1 * bch2u(A1.z) + w2 * bch2u(A2.z) + w3 * bch2u(A3.z));
                m3 = __builtin_elementwise_max(m3, w0 * bch2u(A0.w) + w1 * bch2u(A1.w) + w2 * bch2u(A2.w) + w3 * bch2u(A3.w));
            }
            {
                const h2 w0 = bch2u(wb.x), w1 = bch2u(wb.y), w2 = bch2u(wb.z), w3 = bch2u(wb.w);
                m0 = __builtin_elementwise_max(m0, w0 * bch2u(B0.x) + w1 * bch2u(B1.x) + w2 * bch2u(B2.x) + w3 * bch2u(B3.x));
                m1 = __builtin_elementwise_max(m1, w0 * bch2u(B0.y) + w1 * bch2u(B1.y) + w2 * bch2u(B2.y) + w3 * bch2u(B3.y));
                m2 = __builtin_elementwise_max(m2, w0 * bch2u(B0.z) + w1 * bch2u(B1.z) + w2 * bch2u(B2.z) + w3 * bch2u(B3.z));
                m3 = __builtin_elementwise_max(m3, w0 * bch2u(B0.w) + w1 * bch2u(B1.w) + w2 * bch2u(B2.w) + w3 * bch2u(B3.w));
            }
        }

        // lane writes its 8 channels: two 8B-aligned ds_write_b64 (conflict-free)
        _Float16* dst = &outtile[cl * OTP + 8 * lane];
        uint2 lo, hi;
        lo.x = bcu(m0); lo.y = bcu(m1);
        hi.x = bcu(m2); hi.y = bcu(m3);
        *(uint2*)dst       = lo;
        *(uint2*)(dst + 4) = hi;
    }
    __syncthreads();

    // --- flush: [cl][c] -> out[n][c][cellLo+cl], coalesced dword stores ---
    float* dstb = out + (size_t)n * (C_ * NCELL) + cellLo;
    for (int f = tid; f < C_ * CPB; f += 512) {
        const int c = f / CPB, cl = f - CPB * c;   // div by compile-time 25
        __builtin_nontemporal_store((float)outtile[cl * OTP + c], &dstb[c * NCELL + cl]);
    }
}

// ---------------------------------------------------------------------------
// Fallback (reads original (C,H*W) f32 layout directly) — only if d_ws tiny.
// ---------------------------------------------------------------------------
__global__ __launch_bounds__(256) void croppool_fallback(
    const float* __restrict__ src, const float* __restrict__ rois,
    float* __restrict__ out) {

    const int n  = blockIdx.x >> 2;
    const int cq = blockIdx.x & 3;
    const int cbase = cq * 128;
    const int tid = threadIdx.x;

    __shared__ float outtile[128 * NCELL];
    __shared__ int   xi0[PRE], xi1[PRE], yi0[PRE], yi1[PRE];
    __shared__ float xw0[PRE], xw1[PRE], yw0[PRE], yw1[PRE];

    if (tid < 2 * PRE) {
        const int  j   = tid % PRE;
        const bool isy = tid >= PRE;
        const float r1 = rois[n * 5 + (isy ? 2 : 1)] * 0.0625f;
        const float r2 = rois[n * 5 + (isy ? 4 : 3)] * 0.0625f;
        const float sz = isy ? (float)(H_ - 1) : (float)(W_ - 1);
        const int  szi = isy ? (H_ - 1) : (W_ - 1);
        const float t0 = (r2 - r1) / sz;
        const float tc = (r1 + r2 - sz) / sz;
        const float base = -1.0f + (float)j * (2.0f / 13.0f);
        const float coord = (t0 * base + tc + 1.0f) * 0.5f * sz;
        const float f = floorf(coord);
        const float a = coord - f;
        const int i0 = (int)f;
        const int i1 = i0 + 1;
        const float w0 = (i0 >= 0 && i0 <= szi) ? (1.0f - a) : 0.0f;
        const float w1 = (i1 >= 0 && i1 <= szi) ? a : 0.0f;
        const int i0c = min(max(i0, 0), szi);
        const int i1c = min(max(i1, 0), szi);
        if (isy) { yi0[j] = i0c; yi1[j] = i1c; yw0[j] = w0; yw1[j] = w1; }
        else     { xi0[j] = i0c; xi1[j] = i1c; xw0[j] = w0; xw1[j] = w1; }
    }
    __syncthreads();

    const int wave = tid >> 6;
    const int lane = tid & 63;
    const float* srcc = src + (size_t)(cbase + lane) * HW_;

    for (int cell = wave; cell < NCELL; cell += 4) {
        const int py = cell / PS, px = cell % PS;
        float m0 = -FLT_MAX, m1 = -FLT_MAX;
        for (int ry = 0; ry < 2; ++ry) {
            const int gy = 2 * py + ry;
            for (int rx = 0; rx < 2; ++rx) {
                const int gx = 2 * px + rx;
                const int i00 = yi0[gy] * W_ + xi0[gx], i01 = yi0[gy] * W_ + xi1[gx];
                const int i10 = yi1[gy] * W_ + xi0[gx], i11 = yi1[gy] * W_ + xi1[gx];
                const float v0 = yw0[gy] * (xw0[gx] * srcc[i00] + xw1[gx] * srcc[i01])
                               + yw1[gy] * (xw0[gx] * srcc[i10] + xw1[gx] * srcc[i11]);
                const float v1 = yw0[gy] * (xw0[gx] * srcc[64 * HW_ + i00] + xw1[gx] * srcc[64 * HW_ + i01])
                               + yw1[gy] * (xw0[gx] * srcc[64 * HW_ + i10] + xw1[gx] * srcc[64 * HW_ + i11]);
                m0 = fmaxf(m0, v0);
                m1 = fmaxf(m1, v1);
            }
        }
        outtile[lane * NCELL + cell]        = m0;
        outtile[(lane + 64) * NCELL + cell] = m1;
    }
    __syncthreads();

    const vfloat4* lsrc = (const vfloat4*)outtile;
    vfloat4* dst = (vfloat4*)out + (size_t)n * (C_ * NCELL / 4) + cq * (128 * NCELL / 4);
    for (int i = tid; i < 128 * NCELL / 4; i += 256) {
        __builtin_nontemporal_store(lsrc[i], &dst[i]);
    }
}

extern "C" void kernel_launch(void* const* d_in, const int* in_sizes, int n_in,
                              void* d_out, int out_size, void* d_ws, size_t ws_size,
                              hipStream_t stream) {
    const float* bottom = (const float*)d_in[0];   // (1, 512, 38, 50)
    const float* rois   = (const float*)d_in[1];   // (1024, 5)
    float* out = (float*)d_out;                    // (1024, 512, 7, 7)

    const size_t trans_bytes = (size_t)HW_ * C_ * sizeof(_Float16);
    if (ws_size >= trans_bytes) {
        _Float16* trans = (_Float16*)d_ws;
        dim3 tgrid((HW_ + 31) / 32, C_ / 32);
        transpose_kernel<<<tgrid, 256, 0, stream>>>(bottom, trans);
        croppool_kernel<<<dim3(NROIS, 2), 512, 0, stream>>>(trans, rois, out);
    } else {
        croppool_fallback<<<NROIS * 4, 256, 0, stream>>>(bottom, rois, out);
    }
}

// Round 14
// 42.111 us; speedup vs baseline: 2.7474x; 2.7474x over previous
//
#include <hip/hip_runtime.h>
#include <hip/hip_fp16.h>
#include <float.h>

#define C_    512
#define H_    38
#define W_    50
#define HW_   (H_ * W_)       // 1900
#define NROIS 1024
#define PS    7
#define PRE   14              // PS*2
#define NCELL 49              // PS*PS
#define OTP   516             // outtile row stride (halfwords), 8B-aligned rows

typedef float vfloat4 __attribute__((ext_vector_type(4)));
typedef _Float16 h2 __attribute__((ext_vector_type(2)));

__device__ inline h2 bch2u(unsigned v)   { return __builtin_bit_cast(h2, v); }
__device__ inline unsigned bcu(h2 v)     { return __builtin_bit_cast(unsigned, v); }

// ---------------------------------------------------------------------------
// Transpose + downconvert: bottom (C, H*W) f32 -> (H*W, C) fp16.
// ---------------------------------------------------------------------------
__global__ __launch_bounds__(256) void transpose_kernel(
    const float* __restrict__ in, _Float16* __restrict__ out) {
    __shared__ float tile[32][33];
    const int pix0 = blockIdx.x * 32;
    const int c0   = blockIdx.y * 32;
    const int tx = threadIdx.x & 31;
    const int ty = threadIdx.x >> 5;

    for (int i = ty; i < 32; i += 8) {
        int c = c0 + i, pix = pix0 + tx;
        tile[i][tx] = (pix < HW_) ? in[c * HW_ + pix] : 0.0f;
    }
    __syncthreads();
    for (int i = ty; i < 32; i += 8) {
        int pix = pix0 + i, c = c0 + tx;
        if (pix < HW_) out[pix * C_ + c] = (_Float16)tile[tx][i];
    }
}

// ---------------------------------------------------------------------------
// Main crop-and-maxpool kernel (transposed fp16 src: src[pix*512 + c]).
// grid = NROIS; block = 512 (8 waves), one ROI per block.
// Wave covers ALL 512 channels (lane owns 8 ch = 16B): corner load = ONE
// contiguous aligned 1KB single-segment wave-load. Cell body = two
// 2-gridpoint chunks (8 outstanding uint4, ~55 VGPR). Per-axis tables only
// (336 B); per-cell offsets/weights recomputed in VALU (headroom there).
// LDS = 49.7 KB -> 3 blocks/CU; launch_bounds(512,6) -> VGPR cap ~85,
// 24 waves/CU.
// ---------------------------------------------------------------------------
__global__ __launch_bounds__(512, 6) void croppool_kernel(
    const _Float16* __restrict__ src, const float* __restrict__ rois,
    float* __restrict__ out) {

    const int n   = blockIdx.x;
    const int tid = threadIdx.x;

    __shared__ _Float16 outtile[NCELL * OTP];   // 50568 B
    __shared__ int      xo0t[PRE], xo1t[PRE];   // xi*C_
    __shared__ int      yo0t[PRE], yo1t[PRE];   // yi*W_*C_
    __shared__ unsigned xwt[PRE], ywt[PRE];     // h2{w0,w1} per axis point

    // --- per-axis tables (align_corners=True + zeros padding) ---
    if (tid < 2 * PRE) {
        const int  j   = tid % PRE;
        const bool isy = tid >= PRE;
        const float r1 = rois[n * 5 + (isy ? 2 : 1)] * 0.0625f;
        const float r2 = rois[n * 5 + (isy ? 4 : 3)] * 0.0625f;
        const float sz = isy ? (float)(H_ - 1) : (float)(W_ - 1);
        const int  szi = isy ? (H_ - 1) : (W_ - 1);
        const float t0 = (r2 - r1) / sz;
        const float tc = (r1 + r2 - sz) / sz;
        const float base = -1.0f + (float)j * (2.0f / 13.0f);
        const float coord = (t0 * base + tc + 1.0f) * 0.5f * sz;
        const float f = floorf(coord);
        const float a = coord - f;
        const int i0 = (int)f;
        const int i1 = i0 + 1;
        const float w0 = (i0 >= 0 && i0 <= szi) ? (1.0f - a) : 0.0f;
        const float w1 = (i1 >= 0 && i1 <= szi) ? a : 0.0f;
        const int i0c = min(max(i0, 0), szi);
        const int i1c = min(max(i1, 0), szi);
        const unsigned wpk = bcu((h2){(_Float16)w0, (_Float16)w1});
        if (isy) {
            yo0t[j] = i0c * (W_ * C_);
            yo1t[j] = i1c * (W_ * C_);
            ywt[j]  = wpk;
        } else {
            xo0t[j] = i0c * C_;
            xo1t[j] = i1c * C_;
            xwt[j]  = wpk;
        }
    }
    __syncthreads();

    const int lane = tid & 63;
    const int wave = tid >> 6;                 // 0..7
    const _Float16* srcc = src + 8 * lane;     // lane's 8 channels

    for (int cell = wave; cell < NCELL; cell += 8) {
        const int py = cell / PS, px = cell - PS * py;
        const int gx = 2 * px, gy = 2 * py;

        // per-axis data for this cell (wave-uniform LDS broadcasts)
        const int xa0 = xo0t[gx],     xa1 = xo1t[gx];       // gridpoint col gx
        const int xb0 = xo0t[gx + 1], xb1 = xo1t[gx + 1];   // gridpoint col gx+1
        const int ya0 = yo0t[gy],     ya1 = yo1t[gy];       // gridpoint row gy
        const int yb0 = yo0t[gy + 1], yb1 = yo1t[gy + 1];   // gridpoint row gy+1
        const h2 xwa = bch2u(xwt[gx]), xwb = bch2u(xwt[gx + 1]);
        const h2 ywa = bch2u(ywt[gy]), ywb = bch2u(ywt[gy + 1]);

        h2 m0, m1, m2, m3;

        // ---- chunk A: gridpoints (gy,gx) and (gy,gx+1) — 8 loads in flight ----
        {
            const uint4 A0 = *(const uint4*)(srcc + (ya0 + xa0));
            const uint4 A1 = *(const uint4*)(srcc + (ya0 + xa1));
            const uint4 A2 = *(const uint4*)(srcc + (ya1 + xa0));
            const uint4 A3 = *(const uint4*)(srcc + (ya1 + xa1));
            const uint4 B0 = *(const uint4*)(srcc + (ya0 + xb0));
            const uint4 B1 = *(const uint4*)(srcc + (ya0 + xb1));
            const uint4 B2 = *(const uint4*)(srcc + (ya1 + xb0));
            const uint4 B3 = *(const uint4*)(srcc + (ya1 + xb1));

            {
                const _Float16 wy0 = ywa.x, wy1 = ywa.y;
                const _Float16 c00 = wy0 * xwa.x, c01 = wy0 * xwa.y;
                const _Float16 c10 = wy1 * xwa.x, c11 = wy1 * xwa.y;
                const h2 w0 = (h2){c00, c00}, w1 = (h2){c01, c01};
                const h2 w2 = (h2){c10, c10}, w3 = (h2){c11, c11};
                m0 = w0 * bch2u(A0.x) + w1 * bch2u(A1.x) + w2 * bch2u(A2.x) + w3 * bch2u(A3.x);
                m1 = w0 * bch2u(A0.y) + w1 * bch2u(A1.y) + w2 * bch2u(A2.y) + w3 * bch2u(A3.y);
                m2 = w0 * bch2u(A0.z) + w1 * bch2u(A1.z) + w2 * bch2u(A2.z) + w3 * bch2u(A3.z);
                m3 = w0 * bch2u(A0.w) + w1 * bch2u(A1.w) + w2 * bch2u(A2.w) + w3 * bch2u(A3.w);
            }
            {
                const _Float16 wy0 = ywa.x, wy1 = ywa.y;
                const _Float16 c00 = wy0 * xwb.x, c01 = wy0 * xwb.y;
                const _Float16 c10 = wy1 * xwb.x, c11 = wy1 * xwb.y;
                const h2 w0 = (h2){c00, c00}, w1 = (h2){c01, c01};
                const h2 w2 = (h2){c10, c10}, w3 = (h2){c11, c11};
                m0 = __builtin_elementwise_max(m0, w0 * bch2u(B0.x) + w1 * bch2u(B1.x) + w2 * bch2u(B2.x) + w3 * bch2u(B3.x));
                m1 = __builtin_elementwise_max(m1, w0 * bch2u(B0.y) + w1 * bch2u(B1.y) + w2 * bch2u(B2.y) + w3 * bch2u(B3.y));
                m2 = __builtin_elementwise_max(m2, w0 * bch2u(B0.z) + w1 * bch2u(B1.z) + w2 * bch2u(B2.z) + w3 * bch2u(B3.z));
                m3 = __builtin_elementwise_max(m3, w0 * bch2u(B0.w) + w1 * bch2u(B1.w) + w2 * bch2u(B2.w) + w3 * bch2u(B3.w));
            }
        }

        // ---- chunk B: gridpoints (gy+1,gx) and (gy+1,gx+1) ----
        {
            const uint4 A0 = *(const uint4*)(srcc + (yb0 + xa0));
            const uint4 A1 = *(const uint4*)(srcc + (yb0 + xa1));
            const uint4 A2 = *(const uint4*)(srcc + (yb1 + xa0));
            const uint4 A3 = *(const uint4*)(srcc + (yb1 + xa1));
            const uint4 B0 = *(const uint4*)(srcc + (yb0 + xb0));
            const uint4 B1 = *(const uint4*)(srcc + (yb0 + xb1));
            const uint4 B2 = *(const uint4*)(srcc + (yb1 + xb0));
            const uint4 B3 = *(const uint4*)(srcc + (yb1 + xb1));

            {
                const _Float16 wy0 = ywb.x, wy1 = ywb.y;
                const _Float16 c00 = wy0 * xwa.x, c01 = wy0 * xwa.y;
                const _Float16 c10 = wy1 * xwa.x, c11 = wy1 * xwa.y;
                const h2 w0 = (h2){c00, c00}, w1 = (h2){c01, c01};
                const h2 w2 = (h2){c10, c10}, w3 = (h2){c11, c11};
                m0 = __builtin_elementwise_max(m0, w0 * bch2u(A0.x) + w1 * bch2u(A1.x) + w2 * bch2u(A2.x) + w3 * bch2u(A3.x));
                m1 = __builtin_elementwise_max(m1, w0 * bch2u(A0.y) + w1 * bch2u(A1.y) + w2 * bch2u(A2.y) + w3 * bch2u(A3.y));
                m2 = __builtin_elementwise_max(m2, w0 * bch2u(A0.z) + w1 * bch2u(A1.z) + w2 * bch2u(A2.z) + w3 * bch2u(A3.z));
                m3 = __builtin_elementwise_max(m3, w0 * bch2u(A0.w) + w1 * bch2u(A1.w) + w2 * bch2u(A2.w) + w3 * bch2u(A3.w));
            }
            {
                const _Float16 wy0 = ywb.x, wy1 = ywb.y;
                const _Float16 c00 = wy0 * xwb.x, c01 = wy0 * xwb.y;
                const _Float16 c10 = wy1 * xwb.x, c11 = wy1 * xwb.y;
                const h2 w0 = (h2){c00, c00}, w1 = (h2){c01, c01};
                const h2 w2 = (h2){c10, c10}, w3 = (h2){c11, c11};
                m0 = __builtin_elementwise_max(m0, w0 * bch2u(B0.x) + w1 * bch2u(B1.x) + w2 * bch2u(B2.x) + w3 * bch2u(B3.x));
                m1 = __builtin_elementwise_max(m1, w0 * bch2u(B0.y) + w1 * bch2u(B1.y) + w2 * bch2u(B2.y) + w3 * bch2u(B3.y));
                m2 = __builtin_elementwise_max(m2, w0 * bch2u(B0.z) + w1 * bch2u(B1.z) + w2 * bch2u(B2.z) + w3 * bch2u(B3.z));
                m3 = __builtin_elementwise_max(m3, w0 * bch2u(B0.w) + w1 * bch2u(B1.w) + w2 * bch2u(B2.w) + w3 * bch2u(B3.w));
            }
        }

        // lane writes its 8 channels: two 8B-aligned ds_write_b64
        _Float16* dst = &outtile[cell * OTP + 8 * lane];
        uint2 lo, hi;
        lo.x = bcu(m0); lo.y = bcu(m1);
        hi.x = bcu(m2); hi.y = bcu(m3);
        *(uint2*)dst       = lo;
        *(uint2*)(dst + 4) = hi;
    }
    __syncthreads();

    // --- flush: [cell][c] -> out[n][c][cell], contiguous dword stores ---
    float* dstb = out + (size_t)n * (C_ * NCELL);
    for (int f = tid; f < C_ * NCELL; f += 512) {
        const int c = f / NCELL, cell = f - NCELL * c;
        __builtin_nontemporal_store((float)outtile[cell * OTP + c], &dstb[f]);
    }
}

// ---------------------------------------------------------------------------
// Fallback (reads original (C,H*W) f32 layout directly) — only if d_ws tiny.
// ---------------------------------------------------------------------------
__global__ __launch_bounds__(256) void croppool_fallback(
    const float* __restrict__ src, const float* __restrict__ rois,
    float* __restrict__ out) {

    const int n  = blockIdx.x >> 2;
    const int cq = blockIdx.x & 3;
    const int cbase = cq * 128;
    const int tid = threadIdx.x;

    __shared__ float outtile[128 * NCELL];
    __shared__ int   xi0[PRE], xi1[PRE], yi0[PRE], yi1[PRE];
    __shared__ float xw0[PRE], xw1[PRE], yw0[PRE], yw1[PRE];

    if (tid < 2 * PRE) {
        const int  j   = tid % PRE;
        const bool isy = tid >= PRE;
        const float r1 = rois[n * 5 + (isy ? 2 : 1)] * 0.0625f;
        const float r2 = rois[n * 5 + (isy ? 4 : 3)] * 0.0625f;
        const float sz = isy ? (float)(H_ - 1) : (float)(W_ - 1);
        const int  szi = isy ? (H_ - 1) : (W_ - 1);
        const float t0 = (r2 - r1) / sz;
        const float tc = (r1 + r2 - sz) / sz;
        const float base = -1.0f + (float)j * (2.0f / 13.0f);
        const float coord = (t0 * base + tc + 1.0f) * 0.5f * sz;
        const float f = floorf(coord);
        const float a = coord - f;
        const int i0 = (int)f;
        const int i1 = i0 + 1;
        const float w0 = (i0 >= 0 && i0 <= szi) ? (1.0f - a) : 0.0f;
        const float w1 = (i1 >= 0 && i1 <= szi) ? a : 0.0f;
        const int i0c = min(max(i0, 0), szi);
        const int i1c = min(max(i1, 0), szi);
        if (isy) { yi0[j] = i0c; yi1[j] = i1c; yw0[j] = w0; yw1[j] = w1; }
        else     { xi0[j] = i0c; xi1[j] = i1c; xw0[j] = w0; xw1[j] = w1; }
    }
    __syncthreads();

    const int wave = tid >> 6;
    const int lane = tid & 63;
    const float* srcc = src + (size_t)(cbase + lane) * HW_;

    for (int cell = wave; cell < NCELL; cell += 4) {
        const int py = cell / PS, px = cell % PS;
        float m0 = -FLT_MAX, m1 = -FLT_MAX;
        for (int ry = 0; ry < 2; ++ry) {
            const int gy = 2 * py + ry;
            for (int rx = 0; rx < 2; ++rx) {
                const int gx = 2 * px + rx;
                const int i00 = yi0[gy] * W_ + xi0[gx], i01 = yi0[gy] * W_ + xi1[gx];
                const int i10 = yi1[gy] * W_ + xi0[gx], i11 = yi1[gy] * W_ + xi1[gx];
                const float v0 = yw0[gy] * (xw0[gx] * srcc[i00] + xw1[gx] * srcc[i01])
                               + yw1[gy] * (xw0[gx] * srcc[i10] + xw1[gx] * srcc[i11]);
                const float v1 = yw0[gy] * (xw0[gx] * srcc[64 * HW_ + i00] + xw1[gx] * srcc[64 * HW_ + i01])
                               + yw1[gy] * (xw0[gx] * srcc[64 * HW_ + i10] + xw1[gx] * srcc[64 * HW_ + i11]);
                m0 = fmaxf(m0, v0);
                m1 = fmaxf(m1, v1);
            }
        }
        outtile[lane * NCELL + cell]        = m0;
        outtile[(lane + 64) * NCELL + cell] = m1;
    }
    __syncthreads();

    const vfloat4* lsrc = (const vfloat4*)outtile;
    vfloat4* dst = (vfloat4*)out + (size_t)n * (C_ * NCELL / 4) + cq * (128 * NCELL / 4);
    for (int i = tid; i < 128 * NCELL / 4; i += 256) {
        __builtin_nontemporal_store(lsrc[i], &dst[i]);
    }
}

extern "C" void kernel_launch(void* const* d_in, const int* in_sizes, int n_in,
                              void* d_out, int out_size, void* d_ws, size_t ws_size,
                              hipStream_t stream) {
    const float* bottom = (const float*)d_in[0];   // (1, 512, 38, 50)
    const float* rois   = (const float*)d_in[1];   // (1024, 5)
    float* out = (float*)d_out;                    // (1024, 512, 7, 7)

    const size_t trans_bytes = (size_t)HW_ * C_ * sizeof(_Float16);
    if (ws_size >= trans_bytes) {
        _Float16* trans = (_Float16*)d_ws;
        dim3 tgrid((HW_ + 31) / 32, C_ / 32);
        transpose_kernel<<<tgrid, 256, 0, stream>>>(bottom, trans);
        croppool_kernel<<<NROIS, 512, 0, stream>>>(trans, rois, out);
    } else {
        croppool_fallback<<<NROIS * 4, 256, 0, stream>>>(bottom, rois, out);
    }
}